// Round 8
// baseline (111.330 us; speedup 1.0000x reference)
//
#include <hip/hip_runtime.h>

// Problem constants (from reference): B=8, C=256, O=8, H=W=64, G=8
#define BB   8
#define CC   256
#define OO   8
#define GG   8
#define HW   4096        // 64*64
#define NCH  4           // channels per block (same group -> shared offsets)

typedef float f32x4_t __attribute__((ext_vector_type(4)));

// f32 -> bf16 bits (round-to-nearest-even), result in low 16 bits
static __device__ __forceinline__ unsigned f2bf_u(float f) {
    unsigned u = __float_as_uint(f);
    u += 0x7FFFu + ((u >> 16) & 1u);
    return u >> 16;
}
static __device__ __forceinline__ float bflo(unsigned u) {   // low bf16 -> f32
    return __uint_as_float(u << 16);
}
static __device__ __forceinline__ float bfhi(unsigned u) {   // high bf16 -> f32
    return __uint_as_float(u & 0xFFFF0000u);
}

// Round-7 structure, single-variable A/B: TEMPORAL stores (nt removed).
// Isolates the nontemporal-store flag, which entered bundled with the
// packed-pair LDS win in round 4. Harness fill kernels reach 7.0 TB/s with
// temporal stores; if L2 write-aggregation helps our stream too, this wins;
// if the nt pollution-relief was real, this loses a hair. Null/worse ->
// declare roofline at 93.3 us (93% of 6.29 TB/s copy ceiling).
__global__ __launch_bounds__(256, 4) void deo_kernel(const float* __restrict__ x,
                                                     const float* __restrict__ off,
                                                     float* __restrict__ out) {
    __shared__ unsigned lds[4 * OO * 256];   // 32 KB

    const int tid = threadIdx.x;
    const int bid = blockIdx.x;

    // bid = ((b*4 + tile)*8 + g)*8 + chunk  (chunk fastest: 8 consecutive
    // blocks share one offset tile in L2)
    const int chunk = bid & 7;
    const int g     = (bid >> 3) & 7;
    const int tile  = (bid >> 6) & 3;
    const int b     = bid >> 8;

    const int c0  = g * 32 + chunk * NCH;
    const int hw0 = tile * 1024 + tid * 4;

    const float* op = off + ((size_t)(b * GG + g)) * (OO * HW) + hw0;

    // ---- precompute packed (lds word idx | bf16 w1) per element ----
    unsigned pw[OO][4];
#pragma unroll
    for (int o = 0; o < OO; ++o) {
        const float4 w = *(const float4*)(op + o * HW);
        const float wv[4] = {w.x, w.y, w.z, w.w};
#pragma unroll
        for (int j = 0; j < 4; ++j) {
            const float pv = (float)o + wv[j];
            const float p0 = floorf(pv);
            const float w1 = pv - p0;
            const int   i0 = ((int)p0) & 7;               // cyclic wrap
            const unsigned idx = (unsigned)((j * OO + i0) * 256 + tid);
            pw[o][j] = idx | (f2bf_u(w1) << 16);
        }
    }

    // ---- channel loop (not unrolled: keep VGPR peak low) ----
#pragma unroll 1
    for (int ch = 0; ch < NCH; ++ch) {
        const size_t base = ((size_t)(b * CC + c0 + ch)) * (OO * HW) + hw0;
        const float* xp = x   + base;
        float*       yp = out + base;

        float4 xv[OO];
#pragma unroll
        for (int o = 0; o < OO; ++o) xv[o] = *(const float4*)(xp + o * HW);

        unsigned h[OO][4];
#pragma unroll
        for (int o = 0; o < OO; ++o) {
            h[o][0] = f2bf_u(xv[o].x);
            h[o][1] = f2bf_u(xv[o].y);
            h[o][2] = f2bf_u(xv[o].z);
            h[o][3] = f2bf_u(xv[o].w);
        }
#pragma unroll
        for (int o = 0; o < OO; ++o) {
            const int on = (o + 1) & 7;
#pragma unroll
            for (int j = 0; j < 4; ++j)
                lds[(j * OO + o) * 256 + tid] = h[o][j] | (h[on][j] << 16);
        }
        // no barrier: private-column access pattern

#pragma unroll
        for (int o = 0; o < OO; ++o) {
            f32x4_t r;
#pragma unroll
            for (int j = 0; j < 4; ++j) {
                const unsigned pwv = pw[o][j];
                const unsigned u   = lds[pwv & 0xFFFFu];
                const float w1 = bfhi(pwv);               // bf16 weight
                const float a  = bflo(u);                 // x[i0]
                const float bb = bfhi(u);                 // x[(i0+1)&7]
                r[j] = fmaf(w1, bb - a, a);
            }
            *(f32x4_t*)(yp + o * HW) = r;                 // temporal store (A/B)
        }
    }
}

extern "C" void kernel_launch(void* const* d_in, const int* in_sizes, int n_in,
                              void* d_out, int out_size, void* d_ws, size_t ws_size,
                              hipStream_t stream) {
    const float* x   = (const float*)d_in[0];
    const float* off = (const float*)d_in[1];
    float*       out = (float*)d_out;

    const int blocks = BB * 4 * GG * (32 / NCH);   // 2048
    deo_kernel<<<blocks, 256, 0, stream>>>(x, off, out);
}

// Round 9
// 93.353 us; speedup vs baseline: 1.1926x; 1.1926x over previous
//
#include <hip/hip_runtime.h>

// Problem constants (from reference): B=8, C=256, O=8, H=W=64, G=8
#define BB   8
#define CC   256
#define OO   8
#define GG   8
#define HW   4096        // 64*64
#define NCH  4           // channels per block (same group -> shared offsets)

typedef float f32x4_t __attribute__((ext_vector_type(4)));

// f32 -> bf16 bits (round-to-nearest-even), result in low 16 bits
static __device__ __forceinline__ unsigned f2bf_u(float f) {
    unsigned u = __float_as_uint(f);
    u += 0x7FFFu + ((u >> 16) & 1u);
    return u >> 16;
}
static __device__ __forceinline__ float bflo(unsigned u) {   // low bf16 -> f32
    return __uint_as_float(u << 16);
}
static __device__ __forceinline__ float bfhi(unsigned u) {   // high bf16 -> f32
    return __uint_as_float(u & 0xFFFF0000u);
}

// BEST CONFIG (round 7: 93.3 us = ~93% of the 6.29 TB/s copy ceiling).
// Experiment ledger:
//   + packed bf16-pair LDS (one ds_read_b32 -> both lerp endpoints): +14 us
//   + NONTEMPORAL out stores: +18 us (isolated round-8 A/B; temporal stores
//     write-allocate 262 MB in L2/L3 and evict the ~110 MB of x that L3
//     retains across replays -> FETCH rises -> 111 us)
//   o occupancy 20->32 waves/CU: null (not latency-bound)
//   o offset amortization NCH=4 (268->67 MB logical): null (L3 absorbed it)
//   - XCD swizzle + nt x-loads: -23 us (stream scattering + lost retention)
__global__ __launch_bounds__(256, 4) void deo_kernel(const float* __restrict__ x,
                                                     const float* __restrict__ off,
                                                     float* __restrict__ out) {
    __shared__ unsigned lds[4 * OO * 256];   // 32 KB

    const int tid = threadIdx.x;
    const int bid = blockIdx.x;

    // bid = ((b*4 + tile)*8 + g)*8 + chunk  (chunk fastest: 8 consecutive
    // blocks share one offset tile in L2)
    const int chunk = bid & 7;
    const int g     = (bid >> 3) & 7;
    const int tile  = (bid >> 6) & 3;
    const int b     = bid >> 8;

    const int c0  = g * 32 + chunk * NCH;
    const int hw0 = tile * 1024 + tid * 4;

    const float* op = off + ((size_t)(b * GG + g)) * (OO * HW) + hw0;

    // ---- precompute packed (lds word idx | bf16 w1) per element ----
    unsigned pw[OO][4];
#pragma unroll
    for (int o = 0; o < OO; ++o) {
        const float4 w = *(const float4*)(op + o * HW);
        const float wv[4] = {w.x, w.y, w.z, w.w};
#pragma unroll
        for (int j = 0; j < 4; ++j) {
            const float pv = (float)o + wv[j];
            const float p0 = floorf(pv);
            const float w1 = pv - p0;
            const int   i0 = ((int)p0) & 7;               // cyclic wrap
            const unsigned idx = (unsigned)((j * OO + i0) * 256 + tid);
            pw[o][j] = idx | (f2bf_u(w1) << 16);
        }
    }

    // ---- channel loop (not unrolled: keep VGPR peak low) ----
#pragma unroll 1
    for (int ch = 0; ch < NCH; ++ch) {
        const size_t base = ((size_t)(b * CC + c0 + ch)) * (OO * HW) + hw0;
        const float* xp = x   + base;
        float*       yp = out + base;

        float4 xv[OO];
#pragma unroll
        for (int o = 0; o < OO; ++o) xv[o] = *(const float4*)(xp + o * HW);

        unsigned h[OO][4];
#pragma unroll
        for (int o = 0; o < OO; ++o) {
            h[o][0] = f2bf_u(xv[o].x);
            h[o][1] = f2bf_u(xv[o].y);
            h[o][2] = f2bf_u(xv[o].z);
            h[o][3] = f2bf_u(xv[o].w);
        }
#pragma unroll
        for (int o = 0; o < OO; ++o) {
            const int on = (o + 1) & 7;
#pragma unroll
            for (int j = 0; j < 4; ++j)
                lds[(j * OO + o) * 256 + tid] = h[o][j] | (h[on][j] << 16);
        }
        // no barrier: private-column access pattern

#pragma unroll
        for (int o = 0; o < OO; ++o) {
            f32x4_t r;
#pragma unroll
            for (int j = 0; j < 4; ++j) {
                const unsigned pwv = pw[o][j];
                const unsigned u   = lds[pwv & 0xFFFFu];
                const float w1 = bfhi(pwv);               // bf16 weight
                const float a  = bflo(u);                 // x[i0]
                const float bb = bfhi(u);                 // x[(i0+1)&7]
                r[j] = fmaf(w1, bb - a, a);
            }
            __builtin_nontemporal_store(r, (f32x4_t*)(yp + o * HW));
        }
    }
}

extern "C" void kernel_launch(void* const* d_in, const int* in_sizes, int n_in,
                              void* d_out, int out_size, void* d_ws, size_t ws_size,
                              hipStream_t stream) {
    const float* x   = (const float*)d_in[0];
    const float* off = (const float*)d_in[1];
    float*       out = (float*)d_out;

    const int blocks = BB * 4 * GG * (32 / NCH);   // 2048
    deo_kernel<<<blocks, 256, 0, stream>>>(x, off, out);
}